// Round 1
// baseline (3604.284 us; speedup 1.0000x reference)
//
#include <hip/hip_runtime.h>
#include <cstdint>
#include <cstddef>

#define HIST    256
#define DMODEL  512
#define DINNER  1024
#define DSTATE  16
#define DTRANK  32
#define OBSDIM  4096
#define OBSOUT  448
#define ADIM    64
#define NLAYERS 4
#define MROWS   8192   // BATCH*HIST

enum { EPI_NONE = 0, EPI_TOK = 1, EPI_SOFTPLUS = 2, EPI_RELU = 3 };

__device__ __forceinline__ float siluf(float x) { return x / (1.f + __expf(-x)); }
__device__ __forceinline__ float softplusf(float x) {
    return fmaxf(x, 0.f) + log1pf(__expf(-fabsf(x)));
}

// C[m*ldc + coff + n] = epi( sum_k A[m*lda + k] * W[n*K + k] )
// M == MROWS (multiple of 64). N arbitrary (predicated). K % 32 == 0.
template<int EPI>
__global__ __launch_bounds__(256)
void gemm_kernel(const float* __restrict__ A, int lda,
                 const float* __restrict__ W,
                 float* __restrict__ C, int ldc, int coff,
                 int N, int K,
                 const float* __restrict__ bias,
                 const float* __restrict__ pos)
{
    // 64x64 tile, BK=32, 256 threads, 4x4 per thread. +4 pad keeps 16B-aligned
    // rows while breaking the 8-way store-bank pattern down to 4-way.
    __shared__ float As[32][68];
    __shared__ float Ws[32][68];
    const int tid = threadIdx.x;
    const int tx = tid & 15, ty = tid >> 4;
    const int m0 = blockIdx.y * 64;
    const int n0 = blockIdx.x * 64;
    const int lr = tid >> 3;          // 0..31
    const int lc = (tid & 7) << 2;    // 0,4,...,28
    float acc[4][4] = {};
    for (int k0 = 0; k0 < K; k0 += 32) {
        const float4 a0 = *(const float4*)(A + (size_t)(m0 + lr) * lda + k0 + lc);
        const float4 a1 = *(const float4*)(A + (size_t)(m0 + lr + 32) * lda + k0 + lc);
        const int w0r = n0 + lr, w1r = n0 + lr + 32;
        float4 b0 = make_float4(0.f, 0.f, 0.f, 0.f);
        float4 b1 = make_float4(0.f, 0.f, 0.f, 0.f);
        if (w0r < N) b0 = *(const float4*)(W + (size_t)w0r * K + k0 + lc);
        if (w1r < N) b1 = *(const float4*)(W + (size_t)w1r * K + k0 + lc);
        __syncthreads();
        As[lc+0][lr] = a0.x; As[lc+1][lr] = a0.y; As[lc+2][lr] = a0.z; As[lc+3][lr] = a0.w;
        As[lc+0][lr+32] = a1.x; As[lc+1][lr+32] = a1.y; As[lc+2][lr+32] = a1.z; As[lc+3][lr+32] = a1.w;
        Ws[lc+0][lr] = b0.x; Ws[lc+1][lr] = b0.y; Ws[lc+2][lr] = b0.z; Ws[lc+3][lr] = b0.w;
        Ws[lc+0][lr+32] = b1.x; Ws[lc+1][lr+32] = b1.y; Ws[lc+2][lr+32] = b1.z; Ws[lc+3][lr+32] = b1.w;
        __syncthreads();
        #pragma unroll
        for (int k = 0; k < 32; ++k) {
            const float4 a4 = *(const float4*)&As[k][ty << 2];
            const float4 b4 = *(const float4*)&Ws[k][tx << 2];
            const float a[4] = {a4.x, a4.y, a4.z, a4.w};
            const float b[4] = {b4.x, b4.y, b4.z, b4.w};
            #pragma unroll
            for (int i = 0; i < 4; ++i)
                #pragma unroll
                for (int j = 0; j < 4; ++j)
                    acc[i][j] = fmaf(a[i], b[j], acc[i][j]);
        }
    }
    const int mb = m0 + (ty << 2);
    const int nb = n0 + (tx << 2);
    #pragma unroll
    for (int i = 0; i < 4; ++i) {
        const int m = mb + i;
        #pragma unroll
        for (int j = 0; j < 4; ++j) {
            const int n = nb + j;
            if (n < N) {
                float v = acc[i][j];
                if (EPI == EPI_TOK)           v += bias[n] + pos[(m & (HIST - 1)) * DMODEL + coff + n];
                else if (EPI == EPI_SOFTPLUS) v = softplusf(v + bias[n]);
                else if (EPI == EPI_RELU)     v = fmaxf(v + bias[n], 0.f);
                C[(size_t)m * ldc + coff + n] = v;
            }
        }
    }
}

// x[m, 0:64] = (l==0 ? 0 : act_emb[actions[b, l-1]]) + pos_emb[l, 0:64]
__global__ __launch_bounds__(256)
void embed_kernel(const int* __restrict__ actions, const float* __restrict__ act_emb,
                  const float* __restrict__ pos_emb, float* __restrict__ x)
{
    const int idx = blockIdx.x * 256 + threadIdx.x;   // MROWS*64
    const int e = idx & 63;
    const int m = idx >> 6;
    const int l = m & (HIST - 1);
    const int b = m >> 8;
    float v = pos_emb[l * DMODEL + e];
    if (l > 0) {
        const int a = actions[b * HIST + l - 1];
        v += act_emb[a * ADIM + e];
    }
    x[(size_t)m * DMODEL + e] = v;
}

// xc[m,d] = silu(conv_b[d] + sum_k conv_w[d,k]*xi[l-3+k, d]); xi = xz[:, 0:1024]
__global__ __launch_bounds__(256)
void conv_silu_kernel(const float* __restrict__ xz, const float* __restrict__ cw,
                      const float* __restrict__ cb, float* __restrict__ xc)
{
    const int idx = blockIdx.x * 256 + threadIdx.x;   // MROWS*DINNER
    const int d = idx & (DINNER - 1);
    const int m = idx >> 10;
    const int l = m & (HIST - 1);
    const float4 w = ((const float4*)cw)[d];
    const float* base = xz + (size_t)m * (2 * DINNER) + d;
    float acc = cb[d] + w.w * base[0];
    if (l >= 1) acc = fmaf(w.z, base[-(2 * DINNER)], acc);
    if (l >= 2) acc = fmaf(w.y, base[-2 * (2 * DINNER)], acc);
    if (l >= 3) acc = fmaf(w.x, base[-3 * (2 * DINNER)], acc);
    xc[idx] = siluf(acc);
}

// Selective scan. Wave = 4 channels x 16 states; lane n holds state n of its
// channel. y overwrites dt in place (same (r,d) slot, read-before-write within
// the same iteration; no cross-thread aliasing: one channel-group owns (b,d)).
__global__ __launch_bounds__(256)
void scan_kernel(float* __restrict__ dty, const float* __restrict__ xdbl,
                 const float* __restrict__ xc, const float* __restrict__ xz,
                 const float* __restrict__ A_log, const float* __restrict__ D_p)
{
    const int tid = threadIdx.x;
    const int n = tid & 15;
    const int c = blockIdx.x * 16 + (tid >> 4);  // global channel (b,d)
    const int b = c >> 10;
    const int d = c & (DINNER - 1);
    const float A = -__expf(A_log[d * DSTATE + n]);
    const float Dp = D_p[d];
    float h = 0.f;
    const size_t row0 = (size_t)b * HIST;
    for (int l = 0; l < HIST; ++l) {
        const size_t r = row0 + l;
        const float dt  = dty[r * DINNER + d];
        const float xcv = xc[r * DINNER + d];
        const float Bv  = xdbl[r * 64 + DTRANK + n];
        const float Cv  = xdbl[r * 64 + DTRANK + DSTATE + n];
        const float dA = __expf(dt * A);
        h = fmaf(dA, h, dt * Bv * xcv);
        float contrib = h * Cv;
        contrib += __shfl_xor(contrib, 1);
        contrib += __shfl_xor(contrib, 2);
        contrib += __shfl_xor(contrib, 4);
        contrib += __shfl_xor(contrib, 8);
        if (n == 0) {
            const float z = xz[r * (2 * DINNER) + DINNER + d];
            dty[r * DINNER + d] = (contrib + xcv * Dp) * siluf(z);
        }
    }
}

// out[m,n] = b2[n] + sum_k h[m,k]*W2[n,k];  N=18 packed into 32-thread groups
__global__ __launch_bounds__(256)
void ffn2_kernel(const float* __restrict__ h, const float* __restrict__ W2,
                 const float* __restrict__ b2, float* __restrict__ out)
{
    const int idx = blockIdx.x * 256 + threadIdx.x;   // MROWS*32
    const int n = idx & 31;
    const int m = idx >> 5;
    if (n >= 18) return;
    const float* hr = h + (size_t)m * DMODEL;
    const float* wr = W2 + (size_t)n * DMODEL;
    float acc = b2[n];
    for (int k = 0; k < DMODEL; k += 4) {
        const float4 hv = *(const float4*)(hr + k);
        const float4 wv = *(const float4*)(wr + k);
        acc = fmaf(hv.x, wv.x, acc);
        acc = fmaf(hv.y, wv.y, acc);
        acc = fmaf(hv.z, wv.z, acc);
        acc = fmaf(hv.w, wv.w, acc);
    }
    out[(size_t)m * 18 + n] = acc;
}

static void launch_gemm(int epi, const float* A, int lda, const float* W,
                        float* C, int ldc, int coff, int N, int K,
                        const float* bias, const float* pos, hipStream_t s)
{
    dim3 grid((N + 63) / 64, MROWS / 64);
    dim3 blk(256);
    switch (epi) {
    case EPI_NONE:
        gemm_kernel<EPI_NONE><<<grid, blk, 0, s>>>(A, lda, W, C, ldc, coff, N, K, bias, pos); break;
    case EPI_TOK:
        gemm_kernel<EPI_TOK><<<grid, blk, 0, s>>>(A, lda, W, C, ldc, coff, N, K, bias, pos); break;
    case EPI_SOFTPLUS:
        gemm_kernel<EPI_SOFTPLUS><<<grid, blk, 0, s>>>(A, lda, W, C, ldc, coff, N, K, bias, pos); break;
    case EPI_RELU:
        gemm_kernel<EPI_RELU><<<grid, blk, 0, s>>>(A, lda, W, C, ldc, coff, N, K, bias, pos); break;
    }
}

extern "C" void kernel_launch(void* const* d_in, const int* in_sizes, int n_in,
                              void* d_out, int out_size, void* d_ws, size_t ws_size,
                              hipStream_t stream)
{
    const float* obss    = (const float*)d_in[0];
    const int*   actions = (const int*)  d_in[1];
    const float* obs_W   = (const float*)d_in[2];
    const float* obs_b   = (const float*)d_in[3];
    const float* act_emb = (const float*)d_in[4];
    const float* pos_emb = (const float*)d_in[5];
    const float* W_in    = (const float*)d_in[6];
    const float* conv_w  = (const float*)d_in[7];
    const float* conv_b  = (const float*)d_in[8];
    const float* W_x     = (const float*)d_in[9];
    const float* W_dt    = (const float*)d_in[10];
    const float* b_dt    = (const float*)d_in[11];
    const float* A_log   = (const float*)d_in[12];
    const float* D_p     = (const float*)d_in[13];
    const float* W_out   = (const float*)d_in[14];
    const float* ffn_W1  = (const float*)d_in[15];
    const float* ffn_b1  = (const float*)d_in[16];
    const float* ffn_W2  = (const float*)d_in[17];
    const float* ffn_b2  = (const float*)d_in[18];
    float* out = (float*)d_out;

    float* ws   = (float*)d_ws;
    float* x    = ws;                               // MROWS*512   (16 MB)
    float* xz   = x    + (size_t)MROWS * DMODEL;    // MROWS*2048  (64 MB)
    float* xc   = xz   + (size_t)MROWS * 2 * DINNER;// MROWS*1024  (32 MB)
    float* xdbl = xc   + (size_t)MROWS * DINNER;    // MROWS*64    (2 MB)
    float* dty  = xdbl + (size_t)MROWS * 64;        // MROWS*1024  (32 MB; dt then y)

    // x[:, 0:64] = shifted action embedding + pos_emb
    embed_kernel<<<MROWS * ADIM / 256, 256, 0, stream>>>(actions, act_emb, pos_emb, x);
    // x[:, 64:512] = obss @ obs_W^T + obs_b + pos_emb
    launch_gemm(EPI_TOK, obss, OBSDIM, obs_W, x, DMODEL, ADIM, OBSOUT, OBSDIM,
                obs_b, pos_emb, stream);

    for (int i = 0; i < NLAYERS; ++i) {
        launch_gemm(EPI_NONE, x, DMODEL, W_in + (size_t)i * 2 * DINNER * DMODEL,
                    xz, 2 * DINNER, 0, 2 * DINNER, DMODEL, nullptr, nullptr, stream);
        conv_silu_kernel<<<MROWS * DINNER / 256, 256, 0, stream>>>(
            xz, conv_w + (size_t)i * DINNER * 4, conv_b + (size_t)i * DINNER, xc);
        launch_gemm(EPI_NONE, xc, DINNER, W_x + (size_t)i * 64 * DINNER,
                    xdbl, 64, 0, 64, DINNER, nullptr, nullptr, stream);
        launch_gemm(EPI_SOFTPLUS, xdbl, 64, W_dt + (size_t)i * DINNER * DTRANK,
                    dty, DINNER, 0, DINNER, DTRANK, b_dt + (size_t)i * DINNER, nullptr, stream);
        scan_kernel<<<(32 * DINNER) / 16, 256, 0, stream>>>(
            dty, xdbl, xc, xz, A_log + (size_t)i * DINNER * DSTATE, D_p + (size_t)i * DINNER);
        launch_gemm(EPI_NONE, dty, DINNER, W_out + (size_t)i * DMODEL * DINNER,
                    x, DMODEL, 0, DMODEL, DINNER, nullptr, nullptr, stream);
    }

    float* hbuf = xz;  // reuse xz for FFN hidden (needs MROWS*512 <= MROWS*2048)
    launch_gemm(EPI_RELU, x, DMODEL, ffn_W1, hbuf, DMODEL, 0, DMODEL, DMODEL,
                ffn_b1, nullptr, stream);
    ffn2_kernel<<<MROWS * 32 / 256, 256, 0, stream>>>(hbuf, ffn_W2, ffn_b2, out);
}

// Round 2
// 2095.950 us; speedup vs baseline: 1.7196x; 1.7196x over previous
//
#include <hip/hip_runtime.h>
#include <hip/hip_bf16.h>
#include <cstdint>
#include <cstddef>

#define HIST    256
#define DMODEL  512
#define DINNER  1024
#define DSTATE  16
#define DTRANK  32
#define OBSDIM  4096
#define OBSOUT  448
#define ADIM    64
#define NLAYERS 4
#define MROWS   8192   // BATCH*HIST

typedef __bf16  bf16x8 __attribute__((ext_vector_type(8)));
typedef float   f32x4  __attribute__((ext_vector_type(4)));

enum { EPI_NONE = 0, EPI_SOFTPLUS = 2 };           // f32 path
enum { MEPI_NONE = 0, MEPI_TOK = 1, MEPI_RELU = 2 }; // mfma path

__device__ __forceinline__ float siluf(float x) { return x / (1.f + __expf(-x)); }
__device__ __forceinline__ float softplusf(float x) {
    return fmaxf(x, 0.f) + log1pf(__expf(-fabsf(x)));
}

// ---------------------------------------------------------------------------
// bf16 MFMA GEMM: C = A(MxK) * W^T (W is Npad x K row-major bf16, Npad = 128*gx)
// 128x128 tile, BK=32, 4 waves each computing a 64x64 subtile as 4x4 MFMAs of
// 16x16x32. Staging via global_load_lds width=16 (m97 structure):
//   wave wv stages rows [t*64 + wv*16, +16) of A and W tiles; lane l supplies
//   row (l>>2), col (l&3)*8 -> LDS lands at wave_base + l*16 (wave-uniform).
// Fragment reads: A[m=lane&15][k=(lane>>4)*8+j], C/D row=(lane>>4)*4+r, col=lane&15.
template<int EPI>
__global__ __launch_bounds__(256)
void gemm_mfma(const __hip_bfloat16* __restrict__ A, int lda,
               const __hip_bfloat16* __restrict__ W,
               float* __restrict__ Cf, int ldc,
               __hip_bfloat16* __restrict__ Cb, int ldcb,
               int coff, int N, int K,
               const float* __restrict__ bias, const float* __restrict__ pos)
{
    __shared__ __hip_bfloat16 Asm[128 * 32];
    __shared__ __hip_bfloat16 Bsm[128 * 32];
    const int tid  = threadIdx.x;
    const int lane = tid & 63;
    const int wv   = tid >> 6;
    const int m0   = blockIdx.y * 128;
    const int n0   = blockIdx.x * 128;
    const int wm   = (wv >> 1) << 6;
    const int wn   = (wv & 1) << 6;
    const int sr   = lane >> 2;        // staging row within 16
    const int sc   = (lane & 3) << 3;  // staging col (elements)
    const int quad = lane >> 4;
    const int c16  = lane & 15;

    f32x4 acc[4][4] = {};
    const __hip_bfloat16* aptr = A + (size_t)(m0 + wv * 16 + sr) * lda + sc;
    const __hip_bfloat16* bptr = W + (size_t)(n0 + wv * 16 + sr) * K + sc;
    __hip_bfloat16* asml = Asm + wv * 16 * 32;
    __hip_bfloat16* bsml = Bsm + wv * 16 * 32;

    for (int k0 = 0; k0 < K; k0 += 32) {
        __syncthreads();
        __builtin_amdgcn_global_load_lds(
            (const __attribute__((address_space(1))) void*)(aptr + k0),
            (__attribute__((address_space(3))) void*)(asml), 16, 0, 0);
        __builtin_amdgcn_global_load_lds(
            (const __attribute__((address_space(1))) void*)(aptr + (size_t)64 * lda + k0),
            (__attribute__((address_space(3))) void*)(asml + 64 * 32), 16, 0, 0);
        __builtin_amdgcn_global_load_lds(
            (const __attribute__((address_space(1))) void*)(bptr + k0),
            (__attribute__((address_space(3))) void*)(bsml), 16, 0, 0);
        __builtin_amdgcn_global_load_lds(
            (const __attribute__((address_space(1))) void*)(bptr + (size_t)64 * K + k0),
            (__attribute__((address_space(3))) void*)(bsml + 64 * 32), 16, 0, 0);
        __syncthreads();

        bf16x8 af[4], bf[4];
        #pragma unroll
        for (int i = 0; i < 4; ++i) {
            af[i] = *(const bf16x8*)(Asm + (wm + i * 16 + c16) * 32 + quad * 8);
            bf[i] = *(const bf16x8*)(Bsm + (wn + i * 16 + c16) * 32 + quad * 8);
        }
        #pragma unroll
        for (int i = 0; i < 4; ++i)
            #pragma unroll
            for (int j = 0; j < 4; ++j)
                acc[i][j] = __builtin_amdgcn_mfma_f32_16x16x32_bf16(af[i], bf[j], acc[i][j], 0, 0, 0);
    }

    #pragma unroll
    for (int i = 0; i < 4; ++i) {
        const int mbase = m0 + wm + i * 16 + quad * 4;
        #pragma unroll
        for (int j = 0; j < 4; ++j) {
            const int n = n0 + wn + j * 16 + c16;
            if (n < N) {
                #pragma unroll
                for (int r = 0; r < 4; ++r) {
                    const int m = mbase + r;
                    float v = acc[i][j][r];
                    if (EPI == MEPI_TOK)  v += bias[n] + pos[(m & (HIST - 1)) * DMODEL + coff + n];
                    if (EPI == MEPI_RELU) v = fmaxf(v + bias[n], 0.f);
                    if (Cf) Cf[(size_t)m * ldc + coff + n] = v;
                    if (Cb) Cb[(size_t)m * ldcb + coff + n] = __float2bfloat16(v);
                }
            }
        }
    }
}

// ---------------------------------------------------------------------------
// f32 fallback GEMM (kept for the tiny W_x [N=64] and W_dt [K=32] ops)
template<int EPI>
__global__ __launch_bounds__(256)
void gemm_f32(const float* __restrict__ A, int lda,
              const float* __restrict__ W,
              float* __restrict__ C, int ldc,
              int N, int K, const float* __restrict__ bias)
{
    __shared__ float As[32][68];
    __shared__ float Ws[32][68];
    const int tid = threadIdx.x;
    const int tx = tid & 15, ty = tid >> 4;
    const int m0 = blockIdx.y * 64;
    const int n0 = blockIdx.x * 64;
    const int lr = tid >> 3;
    const int lc = (tid & 7) << 2;
    float acc[4][4] = {};
    for (int k0 = 0; k0 < K; k0 += 32) {
        const float4 a0 = *(const float4*)(A + (size_t)(m0 + lr) * lda + k0 + lc);
        const float4 a1 = *(const float4*)(A + (size_t)(m0 + lr + 32) * lda + k0 + lc);
        const int w0r = n0 + lr, w1r = n0 + lr + 32;
        float4 b0 = make_float4(0.f, 0.f, 0.f, 0.f);
        float4 b1 = make_float4(0.f, 0.f, 0.f, 0.f);
        if (w0r < N) b0 = *(const float4*)(W + (size_t)w0r * K + k0 + lc);
        if (w1r < N) b1 = *(const float4*)(W + (size_t)w1r * K + k0 + lc);
        __syncthreads();
        As[lc+0][lr] = a0.x; As[lc+1][lr] = a0.y; As[lc+2][lr] = a0.z; As[lc+3][lr] = a0.w;
        As[lc+0][lr+32] = a1.x; As[lc+1][lr+32] = a1.y; As[lc+2][lr+32] = a1.z; As[lc+3][lr+32] = a1.w;
        Ws[lc+0][lr] = b0.x; Ws[lc+1][lr] = b0.y; Ws[lc+2][lr] = b0.z; Ws[lc+3][lr] = b0.w;
        Ws[lc+0][lr+32] = b1.x; Ws[lc+1][lr+32] = b1.y; Ws[lc+2][lr+32] = b1.z; Ws[lc+3][lr+32] = b1.w;
        __syncthreads();
        #pragma unroll
        for (int k = 0; k < 32; ++k) {
            const float4 a4 = *(const float4*)&As[k][ty << 2];
            const float4 b4 = *(const float4*)&Ws[k][tx << 2];
            const float a[4] = {a4.x, a4.y, a4.z, a4.w};
            const float b[4] = {b4.x, b4.y, b4.z, b4.w};
            #pragma unroll
            for (int i = 0; i < 4; ++i)
                #pragma unroll
                for (int j = 0; j < 4; ++j)
                    acc[i][j] = fmaf(a[i], b[j], acc[i][j]);
        }
    }
    const int mb = m0 + (ty << 2);
    const int nb = n0 + (tx << 2);
    #pragma unroll
    for (int i = 0; i < 4; ++i) {
        #pragma unroll
        for (int j = 0; j < 4; ++j) {
            const int n = nb + j;
            if (n < N) {
                float v = acc[i][j];
                if (EPI == EPI_SOFTPLUS) v = softplusf(v + bias[n]);
                C[(size_t)(mb + i) * ldc + n] = v;
            }
        }
    }
}

// ---------------------------------------------------------------------------
__global__ __launch_bounds__(256)
void cast_bf16_kernel(const float* __restrict__ src, __hip_bfloat16* __restrict__ dst, int n4)
{
    const int i = blockIdx.x * 256 + threadIdx.x;
    if (i >= n4) return;
    const float4 v = ((const float4*)src)[i];
    union { __hip_bfloat16 h[4]; short4 s; } o;
    o.h[0] = __float2bfloat16(v.x); o.h[1] = __float2bfloat16(v.y);
    o.h[2] = __float2bfloat16(v.z); o.h[3] = __float2bfloat16(v.w);
    ((short4*)dst)[i] = o.s;
}

// cast with zero-padding for rows >= nrows (dst is Npad x K)
__global__ __launch_bounds__(256)
void cast_pad_kernel(const float* __restrict__ src, __hip_bfloat16* __restrict__ dst,
                     int nrows, int K4, int total4)
{
    const int i = blockIdx.x * 256 + threadIdx.x;
    if (i >= total4) return;
    const int row = i / K4;
    float4 v = make_float4(0.f, 0.f, 0.f, 0.f);
    if (row < nrows) v = ((const float4*)src)[i];
    union { __hip_bfloat16 h[4]; short4 s; } o;
    o.h[0] = __float2bfloat16(v.x); o.h[1] = __float2bfloat16(v.y);
    o.h[2] = __float2bfloat16(v.z); o.h[3] = __float2bfloat16(v.w);
    ((short4*)dst)[i] = o.s;
}

// xb[m, 0:64] = bf16( (l==0 ? 0 : act_emb[actions[b,l-1]]) + pos_emb[l, 0:64] )
__global__ __launch_bounds__(256)
void embed_kernel(const int* __restrict__ actions, const float* __restrict__ act_emb,
                  const float* __restrict__ pos_emb, __hip_bfloat16* __restrict__ xb)
{
    const int idx = blockIdx.x * 256 + threadIdx.x;   // MROWS*64
    const int e = idx & 63;
    const int m = idx >> 6;
    const int l = m & (HIST - 1);
    const int b = m >> 8;
    float v = pos_emb[l * DMODEL + e];
    if (l > 0) {
        const int a = actions[b * HIST + l - 1];
        v += act_emb[a * ADIM + e];
    }
    xb[(size_t)m * DMODEL + e] = __float2bfloat16(v);
}

// xc[m,d] = silu(conv_b[d] + sum_k conv_w[d,k]*xi[l-3+k, d]); xi = xz[:, 0:1024]
__global__ __launch_bounds__(256)
void conv_silu_kernel(const float* __restrict__ xz, const float* __restrict__ cw,
                      const float* __restrict__ cb, float* __restrict__ xc)
{
    const int idx = blockIdx.x * 256 + threadIdx.x;   // MROWS*DINNER
    const int d = idx & (DINNER - 1);
    const int m = idx >> 10;
    const int l = m & (HIST - 1);
    const float4 w = ((const float4*)cw)[d];
    const float* base = xz + (size_t)m * (2 * DINNER) + d;
    float acc = cb[d] + w.w * base[0];
    if (l >= 1) acc = fmaf(w.z, base[-(2 * DINNER)], acc);
    if (l >= 2) acc = fmaf(w.y, base[-2 * (2 * DINNER)], acc);
    if (l >= 3) acc = fmaf(w.x, base[-3 * (2 * DINNER)], acc);
    xc[idx] = siluf(acc);
}

// Selective scan: wave = 4 channels x 16 states; output y written as bf16.
__global__ __launch_bounds__(256)
void scan_kernel(const float* __restrict__ dtf, __hip_bfloat16* __restrict__ yb,
                 const float* __restrict__ xdbl, const float* __restrict__ xc,
                 const float* __restrict__ xz,
                 const float* __restrict__ A_log, const float* __restrict__ D_p)
{
    const int tid = threadIdx.x;
    const int n = tid & 15;
    const int c = blockIdx.x * 16 + (tid >> 4);  // global channel (b,d)
    const int b = c >> 10;
    const int d = c & (DINNER - 1);
    const float A = -__expf(A_log[d * DSTATE + n]);
    const float Dp = D_p[d];
    float h = 0.f;
    const size_t row0 = (size_t)b * HIST;
    for (int l = 0; l < HIST; ++l) {
        const size_t r = row0 + l;
        const float dt  = dtf[r * DINNER + d];
        const float xcv = xc[r * DINNER + d];
        const float Bv  = xdbl[r * 64 + DTRANK + n];
        const float Cv  = xdbl[r * 64 + DTRANK + DSTATE + n];
        const float dA = __expf(dt * A);
        h = fmaf(dA, h, dt * Bv * xcv);
        float contrib = h * Cv;
        contrib += __shfl_xor(contrib, 1);
        contrib += __shfl_xor(contrib, 2);
        contrib += __shfl_xor(contrib, 4);
        contrib += __shfl_xor(contrib, 8);
        if (n == 0) {
            const float z = xz[r * (2 * DINNER) + DINNER + d];
            yb[r * DINNER + d] = __float2bfloat16((contrib + xcv * Dp) * siluf(z));
        }
    }
}

// out[m,n] = b2[n] + sum_k h[m,k]*W2[n,k]
__global__ __launch_bounds__(256)
void ffn2_kernel(const float* __restrict__ h, const float* __restrict__ W2,
                 const float* __restrict__ b2, float* __restrict__ out)
{
    const int idx = blockIdx.x * 256 + threadIdx.x;   // MROWS*32
    const int n = idx & 31;
    const int m = idx >> 5;
    if (n >= 18) return;
    const float* hr = h + (size_t)m * DMODEL;
    const float* wr = W2 + (size_t)n * DMODEL;
    float acc = b2[n];
    for (int k = 0; k < DMODEL; k += 4) {
        const float4 hv = *(const float4*)(hr + k);
        const float4 wv = *(const float4*)(wr + k);
        acc = fmaf(hv.x, wv.x, acc);
        acc = fmaf(hv.y, wv.y, acc);
        acc = fmaf(hv.z, wv.z, acc);
        acc = fmaf(hv.w, wv.w, acc);
    }
    out[(size_t)m * 18 + n] = acc;
}

extern "C" void kernel_launch(void* const* d_in, const int* in_sizes, int n_in,
                              void* d_out, int out_size, void* d_ws, size_t ws_size,
                              hipStream_t stream)
{
    const float* obss    = (const float*)d_in[0];
    const int*   actions = (const int*)  d_in[1];
    const float* obs_W   = (const float*)d_in[2];
    const float* obs_b   = (const float*)d_in[3];
    const float* act_emb = (const float*)d_in[4];
    const float* pos_emb = (const float*)d_in[5];
    const float* W_in    = (const float*)d_in[6];
    const float* conv_w  = (const float*)d_in[7];
    const float* conv_b  = (const float*)d_in[8];
    const float* W_x     = (const float*)d_in[9];
    const float* W_dt    = (const float*)d_in[10];
    const float* b_dt    = (const float*)d_in[11];
    const float* A_log   = (const float*)d_in[12];
    const float* D_p     = (const float*)d_in[13];
    const float* W_out   = (const float*)d_in[14];
    const float* ffn_W1  = (const float*)d_in[15];
    const float* ffn_b1  = (const float*)d_in[16];
    const float* ffn_W2  = (const float*)d_in[17];
    const float* ffn_b2  = (const float*)d_in[18];
    float* out = (float*)d_out;

    // Workspace layout (146 MiB total, lifetime-aliased; == round-1 footprint):
    //  [0,32)   MiB: R1 = xb (bf16 x, 8 MiB) / dtf (f32 dt, 32 MiB)  [disjoint lifetimes]
    //  [32,96)  MiB: xz (f32, 64 MiB) / obssb (bf16 obss) / h (FFN hidden)
    //  [96,128) MiB: xc (f32, 32 MiB) / obs_Wb (bf16 padded, 4 MiB)
    //  [128,130)MiB: X = xdbl (f32, 2 MiB) / wbuf (bf16 weight scratch, 2 MiB)
    //  [130,146)MiB: dtyb (bf16 y, 16 MiB)
    const size_t MiB = 1024 * 1024;
    char* base = (char*)d_ws;
    __hip_bfloat16* xb     = (__hip_bfloat16*)(base);
    float*          dtf    = (float*)(base);
    float*          xz     = (float*)(base + 32 * MiB);
    __hip_bfloat16* obssb  = (__hip_bfloat16*)(base + 32 * MiB);
    float*          xc     = (float*)(base + 96 * MiB);
    __hip_bfloat16* obs_Wb = (__hip_bfloat16*)(base + 96 * MiB);
    float*          xdbl   = (float*)(base + 128 * MiB);
    __hip_bfloat16* wbuf   = (__hip_bfloat16*)(base + 128 * MiB);
    __hip_bfloat16* dtyb   = (__hip_bfloat16*)(base + 130 * MiB);
    float*          hbuf   = xz;

    // --- prologue: casts + embedding + tok GEMM ---
    cast_bf16_kernel<<<(MROWS * OBSDIM / 4) / 256, 256, 0, stream>>>(obss, obssb, MROWS * OBSDIM / 4);
    cast_pad_kernel<<<(512 * OBSDIM / 4 + 255) / 256, 256, 0, stream>>>(obs_W, obs_Wb, OBSOUT, OBSDIM / 4, 512 * OBSDIM / 4);
    embed_kernel<<<MROWS * ADIM / 256, 256, 0, stream>>>(actions, act_emb, pos_emb, xb);
    gemm_mfma<MEPI_TOK><<<dim3(4, MROWS / 128), 256, 0, stream>>>(
        obssb, OBSDIM, obs_Wb, (float*)nullptr, 0, xb, DMODEL, ADIM, OBSOUT, OBSDIM, obs_b, pos_emb);

    for (int i = 0; i < NLAYERS; ++i) {
        // W_in cast + GEMM: xz = xb @ W_in^T   (f32 out)
        cast_bf16_kernel<<<(2 * DINNER * DMODEL / 4) / 256, 256, 0, stream>>>(
            W_in + (size_t)i * 2 * DINNER * DMODEL, wbuf, 2 * DINNER * DMODEL / 4);
        gemm_mfma<MEPI_NONE><<<dim3(2 * DINNER / 128, MROWS / 128), 256, 0, stream>>>(
            xb, DMODEL, wbuf, xz, 2 * DINNER, (__hip_bfloat16*)nullptr, 0, 0, 2 * DINNER, DMODEL,
            nullptr, nullptr);
        conv_silu_kernel<<<MROWS * DINNER / 256, 256, 0, stream>>>(
            xz, conv_w + (size_t)i * DINNER * 4, conv_b + (size_t)i * DINNER, xc);
        // W_x (f32): xdbl = xc @ W_x^T  (N=64) — clobbers wbuf (dead)
        gemm_f32<EPI_NONE><<<dim3(1, MROWS / 64), 256, 0, stream>>>(
            xc, DINNER, W_x + (size_t)i * 64 * DINNER, xdbl, 64, 64, DINNER, nullptr);
        // W_dt (f32, softplus): dtf = softplus(xdbl[:, :32] @ W_dt^T + b_dt) — clobbers xb (dead)
        gemm_f32<EPI_SOFTPLUS><<<dim3(DINNER / 64, MROWS / 64), 256, 0, stream>>>(
            xdbl, 64, W_dt + (size_t)i * DINNER * DTRANK, dtf, DINNER, DINNER, DTRANK,
            b_dt + (size_t)i * DINNER);
        scan_kernel<<<(32 * DINNER) / 16, 256, 0, stream>>>(
            dtf, dtyb, xdbl, xc, xz, A_log + (size_t)i * DINNER * DSTATE, D_p + (size_t)i * DINNER);
        // W_out cast + GEMM: xb = bf16(dtyb @ W_out^T) — wbuf clobbers xdbl (dead), xb clobbers dtf (dead)
        cast_bf16_kernel<<<(DMODEL * DINNER / 4) / 256, 256, 0, stream>>>(
            W_out + (size_t)i * DMODEL * DINNER, wbuf, DMODEL * DINNER / 4);
        gemm_mfma<MEPI_NONE><<<dim3(DMODEL / 128, MROWS / 128), 256, 0, stream>>>(
            dtyb, DINNER, wbuf, (float*)nullptr, 0, xb, DMODEL, 0, DMODEL, DINNER,
            nullptr, nullptr);
    }

    // FFN1 (relu, f32 out into hbuf=xz region), then tiny FFN2
    cast_bf16_kernel<<<(DMODEL * DMODEL / 4) / 256, 256, 0, stream>>>(ffn_W1, wbuf, DMODEL * DMODEL / 4);
    gemm_mfma<MEPI_RELU><<<dim3(DMODEL / 128, MROWS / 128), 256, 0, stream>>>(
        xb, DMODEL, wbuf, hbuf, DMODEL, (__hip_bfloat16*)nullptr, 0, 0, DMODEL, DMODEL,
        ffn_b1, nullptr);
    ffn2_kernel<<<MROWS * 32 / 256, 256, 0, stream>>>(hbuf, ffn_W2, ffn_b2, out);
}

// Round 3
// 1640.049 us; speedup vs baseline: 2.1977x; 1.2780x over previous
//
#include <hip/hip_runtime.h>
#include <hip/hip_bf16.h>
#include <cstdint>
#include <cstddef>

#define HIST    256
#define DMODEL  512
#define DINNER  1024
#define DSTATE  16
#define DTRANK  32
#define OBSDIM  4096
#define OBSOUT  448
#define ADIM    64
#define NLAYERS 4
#define MROWS   8192   // BATCH*HIST

typedef __bf16  bf16x8 __attribute__((ext_vector_type(8)));
typedef float   f32x4  __attribute__((ext_vector_type(4)));

enum { MEPI_TOK = 0, MEPI_BF16 = 1, MEPI_XZ = 2, MEPI_RELUF = 3 };
enum { FEPI_SPLIT = 0, FEPI_SOFTPLUS = 1 };

__device__ __forceinline__ float siluf(float x) { return x / (1.f + __expf(-x)); }
__device__ __forceinline__ float softplusf(float x) {
    return fmaxf(x, 0.f) + log1pf(__expf(-fabsf(x)));
}

// ---------------------------------------------------------------------------
// bf16 MFMA GEMM, 128x128 tile, BK=32 (m97-style global_load_lds staging).
template<int EPI>
__global__ __launch_bounds__(256)
void gemm_mfma(const __hip_bfloat16* __restrict__ A, int lda,
               const __hip_bfloat16* __restrict__ W,
               float* __restrict__ Cf, int ldc,
               __hip_bfloat16* __restrict__ Cb, int ldcb,
               int coff, int N, int K,
               const float* __restrict__ bias, const float* __restrict__ pos)
{
    __shared__ __hip_bfloat16 Asm[128 * 32];
    __shared__ __hip_bfloat16 Bsm[128 * 32];
    const int tid  = threadIdx.x;
    const int lane = tid & 63;
    const int wv   = tid >> 6;
    const int m0   = blockIdx.y * 128;
    const int n0   = blockIdx.x * 128;
    const int wm   = (wv >> 1) << 6;
    const int wn   = (wv & 1) << 6;
    const int sr   = lane >> 2;
    const int sc   = (lane & 3) << 3;
    const int quad = lane >> 4;
    const int c16  = lane & 15;

    f32x4 acc[4][4] = {};
    const __hip_bfloat16* aptr = A + (size_t)(m0 + wv * 16 + sr) * lda + sc;
    const __hip_bfloat16* bptr = W + (size_t)(n0 + wv * 16 + sr) * K + sc;
    __hip_bfloat16* asml = Asm + wv * 16 * 32;
    __hip_bfloat16* bsml = Bsm + wv * 16 * 32;

    for (int k0 = 0; k0 < K; k0 += 32) {
        __syncthreads();
        __builtin_amdgcn_global_load_lds(
            (const __attribute__((address_space(1))) void*)(aptr + k0),
            (__attribute__((address_space(3))) void*)(asml), 16, 0, 0);
        __builtin_amdgcn_global_load_lds(
            (const __attribute__((address_space(1))) void*)(aptr + (size_t)64 * lda + k0),
            (__attribute__((address_space(3))) void*)(asml + 64 * 32), 16, 0, 0);
        __builtin_amdgcn_global_load_lds(
            (const __attribute__((address_space(1))) void*)(bptr + k0),
            (__attribute__((address_space(3))) void*)(bsml), 16, 0, 0);
        __builtin_amdgcn_global_load_lds(
            (const __attribute__((address_space(1))) void*)(bptr + (size_t)64 * K + k0),
            (__attribute__((address_space(3))) void*)(bsml + 64 * 32), 16, 0, 0);
        __syncthreads();

        bf16x8 af[4], bfr[4];
        #pragma unroll
        for (int i = 0; i < 4; ++i) {
            af[i]  = *(const bf16x8*)(Asm + (wm + i * 16 + c16) * 32 + quad * 8);
            bfr[i] = *(const bf16x8*)(Bsm + (wn + i * 16 + c16) * 32 + quad * 8);
        }
        #pragma unroll
        for (int i = 0; i < 4; ++i)
            #pragma unroll
            for (int j = 0; j < 4; ++j)
                acc[i][j] = __builtin_amdgcn_mfma_f32_16x16x32_bf16(af[i], bfr[j], acc[i][j], 0, 0, 0);
    }

    #pragma unroll
    for (int i = 0; i < 4; ++i) {
        const int mbase = m0 + wm + i * 16 + quad * 4;
        #pragma unroll
        for (int j = 0; j < 4; ++j) {
            const int n = n0 + wn + j * 16 + c16;
            if (n < N) {
                #pragma unroll
                for (int r = 0; r < 4; ++r) {
                    const int m = mbase + r;
                    float v = acc[i][j][r];
                    if (EPI == MEPI_TOK) {
                        v += bias[n] + pos[(m & (HIST - 1)) * DMODEL + coff + n];
                        Cb[(size_t)m * ldcb + coff + n] = __float2bfloat16(v);
                    } else if (EPI == MEPI_BF16) {
                        Cb[(size_t)m * ldcb + n] = __float2bfloat16(v);
                    } else if (EPI == MEPI_XZ) {
                        if (n < DINNER) Cb[(size_t)m * DINNER + n] = __float2bfloat16(v);
                        else            Cf[(size_t)m * DINNER + (n - DINNER)] = v;
                    } else { // MEPI_RELUF
                        Cf[(size_t)m * ldc + n] = fmaxf(v + bias[n], 0.f);
                    }
                }
            }
        }
    }
}

// ---------------------------------------------------------------------------
// f32 GEMM for the small W_x / W_dt ops.
// FEPI_SPLIT: n<32 -> C[m*ldc+n] (dt_pre); n in [32,64) -> C2 packed float2 (B,C).
template<int EPI>
__global__ __launch_bounds__(256)
void gemm_f32(const float* __restrict__ A, int lda,
              const float* __restrict__ W,
              float* __restrict__ C, int ldc, float* __restrict__ C2,
              int N, int K, const float* __restrict__ bias)
{
    __shared__ float As[32][68];
    __shared__ float Ws[32][68];
    const int tid = threadIdx.x;
    const int tx = tid & 15, ty = tid >> 4;
    const int m0 = blockIdx.y * 64;
    const int n0 = blockIdx.x * 64;
    const int lr = tid >> 3;
    const int lc = (tid & 7) << 2;
    float acc[4][4] = {};
    for (int k0 = 0; k0 < K; k0 += 32) {
        const float4 a0 = *(const float4*)(A + (size_t)(m0 + lr) * lda + k0 + lc);
        const float4 a1 = *(const float4*)(A + (size_t)(m0 + lr + 32) * lda + k0 + lc);
        const int w0r = n0 + lr, w1r = n0 + lr + 32;
        float4 b0 = make_float4(0.f, 0.f, 0.f, 0.f);
        float4 b1 = make_float4(0.f, 0.f, 0.f, 0.f);
        if (w0r < N) b0 = *(const float4*)(W + (size_t)w0r * K + k0 + lc);
        if (w1r < N) b1 = *(const float4*)(W + (size_t)w1r * K + k0 + lc);
        __syncthreads();
        As[lc+0][lr] = a0.x; As[lc+1][lr] = a0.y; As[lc+2][lr] = a0.z; As[lc+3][lr] = a0.w;
        As[lc+0][lr+32] = a1.x; As[lc+1][lr+32] = a1.y; As[lc+2][lr+32] = a1.z; As[lc+3][lr+32] = a1.w;
        Ws[lc+0][lr] = b0.x; Ws[lc+1][lr] = b0.y; Ws[lc+2][lr] = b0.z; Ws[lc+3][lr] = b0.w;
        Ws[lc+0][lr+32] = b1.x; Ws[lc+1][lr+32] = b1.y; Ws[lc+2][lr+32] = b1.z; Ws[lc+3][lr+32] = b1.w;
        __syncthreads();
        #pragma unroll
        for (int k = 0; k < 32; ++k) {
            const float4 a4 = *(const float4*)&As[k][ty << 2];
            const float4 b4 = *(const float4*)&Ws[k][tx << 2];
            const float a[4] = {a4.x, a4.y, a4.z, a4.w};
            const float b[4] = {b4.x, b4.y, b4.z, b4.w};
            #pragma unroll
            for (int i = 0; i < 4; ++i)
                #pragma unroll
                for (int j = 0; j < 4; ++j)
                    acc[i][j] = fmaf(a[i], b[j], acc[i][j]);
        }
    }
    const int mb = m0 + (ty << 2);
    const int nb = n0 + (tx << 2);
    #pragma unroll
    for (int i = 0; i < 4; ++i) {
        const size_t m = mb + i;
        #pragma unroll
        for (int j = 0; j < 4; ++j) {
            const int n = nb + j;
            if (n < N) {
                float v = acc[i][j];
                if (EPI == FEPI_SOFTPLUS) {
                    C[m * ldc + n] = softplusf(v + bias[n]);
                } else { // FEPI_SPLIT
                    if (n < DTRANK) C[m * ldc + n] = v;
                    else C2[m * 32 + ((n & 15) << 1) + ((n >> 4) & 1)] = v;
                }
            }
        }
    }
}

// ---------------------------------------------------------------------------
__global__ __launch_bounds__(256)
void cast_bf16_kernel(const float* __restrict__ src, __hip_bfloat16* __restrict__ dst, int n4)
{
    const int i = blockIdx.x * 256 + threadIdx.x;
    if (i >= n4) return;
    const float4 v = ((const float4*)src)[i];
    union { __hip_bfloat16 h[4]; short4 s; } o;
    o.h[0] = __float2bfloat16(v.x); o.h[1] = __float2bfloat16(v.y);
    o.h[2] = __float2bfloat16(v.z); o.h[3] = __float2bfloat16(v.w);
    ((short4*)dst)[i] = o.s;
}

__global__ __launch_bounds__(256)
void cast_pad_kernel(const float* __restrict__ src, __hip_bfloat16* __restrict__ dst,
                     int nrows, int K4, int total4)
{
    const int i = blockIdx.x * 256 + threadIdx.x;
    if (i >= total4) return;
    const int row = i / K4;
    float4 v = make_float4(0.f, 0.f, 0.f, 0.f);
    if (row < nrows) v = ((const float4*)src)[i];
    union { __hip_bfloat16 h[4]; short4 s; } o;
    o.h[0] = __float2bfloat16(v.x); o.h[1] = __float2bfloat16(v.y);
    o.h[2] = __float2bfloat16(v.z); o.h[3] = __float2bfloat16(v.w);
    ((short4*)dst)[i] = o.s;
}

__global__ __launch_bounds__(256)
void embed_kernel(const int* __restrict__ actions, const float* __restrict__ act_emb,
                  const float* __restrict__ pos_emb, __hip_bfloat16* __restrict__ xb)
{
    const int idx = blockIdx.x * 256 + threadIdx.x;   // MROWS*64
    const int e = idx & 63;
    const int m = idx >> 6;
    const int l = m & (HIST - 1);
    const int b = m >> 8;
    float v = pos_emb[l * DMODEL + e];
    if (l > 0) {
        const int a = actions[b * HIST + l - 1];
        v += act_emb[a * ADIM + e];
    }
    xb[(size_t)m * DMODEL + e] = __float2bfloat16(v);
}

// xc_f[m,d] = silu(conv_b[d] + sum_k conv_w[d,k]*xi[l-3+k, d]); xi bf16 compact
__global__ __launch_bounds__(256)
void conv_silu_kernel(const __hip_bfloat16* __restrict__ xib, const float* __restrict__ cw,
                      const float* __restrict__ cb, float* __restrict__ xcf)
{
    const int idx = blockIdx.x * 256 + threadIdx.x;   // MROWS*DINNER
    const int d = idx & (DINNER - 1);
    const int m = idx >> 10;
    const int l = m & (HIST - 1);
    const float4 w = ((const float4*)cw)[d];
    const __hip_bfloat16* basep = xib + (size_t)m * DINNER + d;
    float acc = cb[d] + w.w * __bfloat162float(basep[0]);
    if (l >= 1) acc = fmaf(w.z, __bfloat162float(basep[-DINNER]), acc);
    if (l >= 2) acc = fmaf(w.y, __bfloat162float(basep[-2 * DINNER]), acc);
    if (l >= 3) acc = fmaf(w.x, __bfloat162float(basep[-3 * DINNER]), acc);
    xcf[idx] = siluf(acc);
}

// ---------------------------------------------------------------------------
// Selective scan, unroll-16. Wave = 4 channels x 16 states (lane&15 = state n).
// Per 16-step block: lane j preloads dt/xc/z for time l0+j; per step a
// ds_swizzle (and=0x10,or=J) broadcasts them to the 16 state-lanes. y_l is
// captured by lane l%16; silu epilogue + store run once per 16 steps.
#define BCAST(v, J) __int_as_float(__builtin_amdgcn_ds_swizzle(__float_as_int(v), ((J) << 5) | 0x10))

__global__ __launch_bounds__(256)
void scan_kernel(const float* __restrict__ dtf, const float* __restrict__ bc,
                 const float* __restrict__ xcf, const float* __restrict__ zf,
                 const float* __restrict__ A_log, const float* __restrict__ D_p,
                 __hip_bfloat16* __restrict__ yb)
{
    const int tid = threadIdx.x;
    const int n = tid & 15;
    const int c = blockIdx.x * 16 + (tid >> 4);  // global channel (b,d)
    const int b = c >> 10;
    const int d = c & (DINNER - 1);
    const float A = -__expf(A_log[d * DSTATE + n]);
    const float Dp = D_p[d];
    float h = 0.f;
    const size_t row0 = (size_t)b * HIST;
    for (int l0 = 0; l0 < HIST; l0 += 16) {
        const size_t rj = row0 + l0 + n;          // this lane's assigned time row
        const float dtv = dtf[rj * DINNER + d];
        const float xcv = xcf[rj * DINNER + d];
        const float zv  = zf [rj * DINNER + d];
        const float* bcp = bc + (row0 + l0) * 32 + 2 * n;
        float yreg = 0.f;
#define STEP(J) { \
        const float dt_ = BCAST(dtv, J); \
        const float xc_ = BCAST(xcv, J); \
        const float2 bcv = *(const float2*)(bcp + (J) * 32); \
        const float dA = __expf(dt_ * A); \
        h = fmaf(dA, h, dt_ * bcv.x * xc_); \
        float ctr = h * bcv.y; \
        ctr += __shfl_xor(ctr, 1); \
        ctr += __shfl_xor(ctr, 2); \
        ctr += __shfl_xor(ctr, 4); \
        ctr += __shfl_xor(ctr, 8); \
        if (n == (J)) yreg = ctr; }
        STEP(0)  STEP(1)  STEP(2)  STEP(3)
        STEP(4)  STEP(5)  STEP(6)  STEP(7)
        STEP(8)  STEP(9)  STEP(10) STEP(11)
        STEP(12) STEP(13) STEP(14) STEP(15)
#undef STEP
        yb[rj * DINNER + d] = __float2bfloat16((yreg + xcv * Dp) * siluf(zv));
    }
}

// out[m,n] = b2[n] + sum_k h[m,k]*W2[n,k]
__global__ __launch_bounds__(256)
void ffn2_kernel(const float* __restrict__ h, const float* __restrict__ W2,
                 const float* __restrict__ b2, float* __restrict__ out)
{
    const int idx = blockIdx.x * 256 + threadIdx.x;   // MROWS*32
    const int n = idx & 31;
    const int m = idx >> 5;
    if (n >= 18) return;
    const float* hr = h + (size_t)m * DMODEL;
    const float* wr = W2 + (size_t)n * DMODEL;
    float acc = b2[n];
    for (int k = 0; k < DMODEL; k += 4) {
        const float4 hv = *(const float4*)(hr + k);
        const float4 wv = *(const float4*)(wr + k);
        acc = fmaf(hv.x, wv.x, acc);
        acc = fmaf(hv.y, wv.y, acc);
        acc = fmaf(hv.z, wv.z, acc);
        acc = fmaf(hv.w, wv.w, acc);
    }
    out[(size_t)m * 18 + n] = acc;
}

extern "C" void kernel_launch(void* const* d_in, const int* in_sizes, int n_in,
                              void* d_out, int out_size, void* d_ws, size_t ws_size,
                              hipStream_t stream)
{
    const float* obss    = (const float*)d_in[0];
    const int*   actions = (const int*)  d_in[1];
    const float* obs_W   = (const float*)d_in[2];
    const float* obs_b   = (const float*)d_in[3];
    const float* act_emb = (const float*)d_in[4];
    const float* pos_emb = (const float*)d_in[5];
    const float* W_in    = (const float*)d_in[6];
    const float* conv_w  = (const float*)d_in[7];
    const float* conv_b  = (const float*)d_in[8];
    const float* W_x     = (const float*)d_in[9];
    const float* W_dt    = (const float*)d_in[10];
    const float* b_dt    = (const float*)d_in[11];
    const float* A_log   = (const float*)d_in[12];
    const float* D_p     = (const float*)d_in[13];
    const float* W_out   = (const float*)d_in[14];
    const float* ffn_W1  = (const float*)d_in[15];
    const float* ffn_b1  = (const float*)d_in[16];
    const float* ffn_W2  = (const float*)d_in[17];
    const float* ffn_b2  = (const float*)d_in[18];
    float* out = (float*)d_out;

    // Workspace (140 MiB, lifetime-aliased):
    //  0-8    xb (bf16 x)          8-24   xib (bf16 xi)      24-56  zf (f32 z)
    //  56-88  xcf (f32 xc)         88-120 dtf (f32 dt)       120-136 yb (bf16 y)
    //  136-137 xdt (f32)           137-138 bcbuf (f32)       138-140 wbuf (bf16)
    //  prologue aliases: obssb @24-88, obs_Wb @88-92; epilogue: hbuf @24-40
    const size_t MiB = 1024 * 1024;
    char* base = (char*)d_ws;
    __hip_bfloat16* xb     = (__hip_bfloat16*)(base);
    __hip_bfloat16* xib    = (__hip_bfloat16*)(base + 8 * MiB);
    float*          zf     = (float*)(base + 24 * MiB);
    float*          xcf    = (float*)(base + 56 * MiB);
    float*          dtf    = (float*)(base + 88 * MiB);
    __hip_bfloat16* yb     = (__hip_bfloat16*)(base + 120 * MiB);
    float*          xdt    = (float*)(base + 136 * MiB);
    float*          bcbuf  = (float*)(base + 137 * MiB);
    __hip_bfloat16* wbuf   = (__hip_bfloat16*)(base + 138 * MiB);
    __hip_bfloat16* obssb  = (__hip_bfloat16*)(base + 24 * MiB);
    __hip_bfloat16* obs_Wb = (__hip_bfloat16*)(base + 88 * MiB);
    float*          hbuf   = (float*)(base + 24 * MiB);

    // --- prologue ---
    cast_bf16_kernel<<<(MROWS * OBSDIM / 4) / 256, 256, 0, stream>>>(obss, obssb, MROWS * OBSDIM / 4);
    cast_pad_kernel<<<(512 * OBSDIM / 4 + 255) / 256, 256, 0, stream>>>(obs_W, obs_Wb, OBSOUT, OBSDIM / 4, 512 * OBSDIM / 4);
    embed_kernel<<<MROWS * ADIM / 256, 256, 0, stream>>>(actions, act_emb, pos_emb, xb);
    gemm_mfma<MEPI_TOK><<<dim3(4, MROWS / 128), 256, 0, stream>>>(
        obssb, OBSDIM, obs_Wb, (float*)nullptr, 0, xb, DMODEL, ADIM, OBSOUT, OBSDIM, obs_b, pos_emb);

    for (int i = 0; i < NLAYERS; ++i) {
        cast_bf16_kernel<<<(2 * DINNER * DMODEL / 4) / 256, 256, 0, stream>>>(
            W_in + (size_t)i * 2 * DINNER * DMODEL, wbuf, 2 * DINNER * DMODEL / 4);
        gemm_mfma<MEPI_XZ><<<dim3(2 * DINNER / 128, MROWS / 128), 256, 0, stream>>>(
            xb, DMODEL, wbuf, zf, 0, xib, 0, 0, 2 * DINNER, DMODEL, nullptr, nullptr);
        conv_silu_kernel<<<MROWS * DINNER / 256, 256, 0, stream>>>(
            xib, conv_w + (size_t)i * DINNER * 4, conv_b + (size_t)i * DINNER, xcf);
        gemm_f32<FEPI_SPLIT><<<dim3(1, MROWS / 64), 256, 0, stream>>>(
            xcf, DINNER, W_x + (size_t)i * 64 * DINNER, xdt, 32, bcbuf, 64, DINNER, nullptr);
        gemm_f32<FEPI_SOFTPLUS><<<dim3(DINNER / 64, MROWS / 64), 256, 0, stream>>>(
            xdt, 32, W_dt + (size_t)i * DINNER * DTRANK, dtf, DINNER, nullptr, DINNER, DTRANK,
            b_dt + (size_t)i * DINNER);
        scan_kernel<<<(32 * DINNER) / 16, 256, 0, stream>>>(
            dtf, bcbuf, xcf, zf, A_log + (size_t)i * DINNER * DSTATE, D_p + (size_t)i * DINNER, yb);
        cast_bf16_kernel<<<(DMODEL * DINNER / 4) / 256, 256, 0, stream>>>(
            W_out + (size_t)i * DMODEL * DINNER, wbuf, DMODEL * DINNER / 4);
        gemm_mfma<MEPI_BF16><<<dim3(DMODEL / 128, MROWS / 128), 256, 0, stream>>>(
            yb, DINNER, wbuf, (float*)nullptr, 0, xb, DMODEL, 0, DMODEL, DINNER, nullptr, nullptr);
    }

    cast_bf16_kernel<<<(DMODEL * DMODEL / 4) / 256, 256, 0, stream>>>(ffn_W1, wbuf, DMODEL * DMODEL / 4);
    gemm_mfma<MEPI_RELUF><<<dim3(DMODEL / 128, MROWS / 128), 256, 0, stream>>>(
        xb, DMODEL, wbuf, hbuf, DMODEL, (__hip_bfloat16*)nullptr, 0, 0, DMODEL, DMODEL,
        ffn_b1, nullptr);
    ffn2_kernel<<<MROWS * 32 / 256, 256, 0, stream>>>(hbuf, ffn_W2, ffn_b2, out);
}

// Round 4
// 1456.214 us; speedup vs baseline: 2.4751x; 1.1262x over previous
//
#include <hip/hip_runtime.h>
#include <hip/hip_bf16.h>
#include <cstdint>
#include <cstddef>

#define HIST    256
#define DMODEL  512
#define DINNER  1024
#define DSTATE  16
#define DTRANK  32
#define OBSDIM  4096
#define OBSOUT  448
#define ADIM    64
#define NLAYERS 4
#define MROWS   8192   // BATCH*HIST

typedef __bf16  bf16x8 __attribute__((ext_vector_type(8)));
typedef float   f32x4  __attribute__((ext_vector_type(4)));

enum { MEPI_TOK = 0, MEPI_BF16 = 1, MEPI_SPLIT = 2, MEPI_RELUF = 3 };

__device__ __forceinline__ float siluf(float x) { return x / (1.f + __expf(-x)); }
__device__ __forceinline__ float softplusf(float x) {
    return fmaxf(x, 0.f) + log1pf(__expf(-fabsf(x)));
}

// ---------------------------------------------------------------------------
// bf16 MFMA GEMM, 128x128 tile, BK=32 (m97-style global_load_lds staging).
// Epilogues:
//  MEPI_TOK  : Cb[m*ldcb+coff+n] = bf16(v + bias[n] + pos[(m%256)*512+coff+n])
//  MEPI_BF16 : Cb[m*ldcb+n] = bf16(v)
//  MEPI_SPLIT: n<32 -> Cf[m*32+n] (dt_pre f32); 32<=n<64 -> C2 packed (B,C)
//  MEPI_RELUF: Cf[m*ldc+n] = relu(v + bias[n])
template<int EPI>
__global__ __launch_bounds__(256)
void gemm_mfma(const __hip_bfloat16* __restrict__ A, int lda,
               const __hip_bfloat16* __restrict__ W,
               float* __restrict__ Cf, int ldc,
               __hip_bfloat16* __restrict__ Cb, int ldcb,
               float* __restrict__ C2,
               int coff, int N, int K,
               const float* __restrict__ bias, const float* __restrict__ pos)
{
    __shared__ __hip_bfloat16 Asm[128 * 32];
    __shared__ __hip_bfloat16 Bsm[128 * 32];
    const int tid  = threadIdx.x;
    const int lane = tid & 63;
    const int wv   = tid >> 6;
    const int m0   = blockIdx.y * 128;
    const int n0   = blockIdx.x * 128;
    const int wm   = (wv >> 1) << 6;
    const int wn   = (wv & 1) << 6;
    const int sr   = lane >> 2;
    const int sc   = (lane & 3) << 3;
    const int quad = lane >> 4;
    const int c16  = lane & 15;

    f32x4 acc[4][4] = {};
    const __hip_bfloat16* aptr = A + (size_t)(m0 + wv * 16 + sr) * lda + sc;
    const __hip_bfloat16* bptr = W + (size_t)(n0 + wv * 16 + sr) * K + sc;
    __hip_bfloat16* asml = Asm + wv * 16 * 32;
    __hip_bfloat16* bsml = Bsm + wv * 16 * 32;

    for (int k0 = 0; k0 < K; k0 += 32) {
        __syncthreads();
        __builtin_amdgcn_global_load_lds(
            (const __attribute__((address_space(1))) void*)(aptr + k0),
            (__attribute__((address_space(3))) void*)(asml), 16, 0, 0);
        __builtin_amdgcn_global_load_lds(
            (const __attribute__((address_space(1))) void*)(aptr + (size_t)64 * lda + k0),
            (__attribute__((address_space(3))) void*)(asml + 64 * 32), 16, 0, 0);
        __builtin_amdgcn_global_load_lds(
            (const __attribute__((address_space(1))) void*)(bptr + k0),
            (__attribute__((address_space(3))) void*)(bsml), 16, 0, 0);
        __builtin_amdgcn_global_load_lds(
            (const __attribute__((address_space(1))) void*)(bptr + (size_t)64 * K + k0),
            (__attribute__((address_space(3))) void*)(bsml + 64 * 32), 16, 0, 0);
        __syncthreads();

        bf16x8 af[4], bfr[4];
        #pragma unroll
        for (int i = 0; i < 4; ++i) {
            af[i]  = *(const bf16x8*)(Asm + (wm + i * 16 + c16) * 32 + quad * 8);
            bfr[i] = *(const bf16x8*)(Bsm + (wn + i * 16 + c16) * 32 + quad * 8);
        }
        #pragma unroll
        for (int i = 0; i < 4; ++i)
            #pragma unroll
            for (int j = 0; j < 4; ++j)
                acc[i][j] = __builtin_amdgcn_mfma_f32_16x16x32_bf16(af[i], bfr[j], acc[i][j], 0, 0, 0);
    }

    #pragma unroll
    for (int i = 0; i < 4; ++i) {
        const int mbase = m0 + wm + i * 16 + quad * 4;
        #pragma unroll
        for (int j = 0; j < 4; ++j) {
            const int n = n0 + wn + j * 16 + c16;
            if (n < N) {
                #pragma unroll
                for (int r = 0; r < 4; ++r) {
                    const size_t m = mbase + r;
                    float v = acc[i][j][r];
                    if (EPI == MEPI_TOK) {
                        v += bias[n] + pos[(m & (HIST - 1)) * DMODEL + coff + n];
                        Cb[m * ldcb + coff + n] = __float2bfloat16(v);
                    } else if (EPI == MEPI_BF16) {
                        Cb[m * ldcb + n] = __float2bfloat16(v);
                    } else if (EPI == MEPI_SPLIT) {
                        if (n < DTRANK) Cf[m * 32 + n] = v;
                        else C2[m * 32 + ((n & 15) << 1) + ((n >> 4) & 1)] = v;
                    } else { // MEPI_RELUF
                        Cf[m * ldc + n] = fmaxf(v + bias[n], 0.f);
                    }
                }
            }
        }
    }
}

// ---------------------------------------------------------------------------
// f32 GEMM for W_dt (K=32): dtf = softplus(xdt @ W_dt^T + b_dt)
__global__ __launch_bounds__(256)
void gemm_f32_sp(const float* __restrict__ A, int lda,
                 const float* __restrict__ W,
                 float* __restrict__ C, int ldc,
                 int N, int K, const float* __restrict__ bias)
{
    __shared__ float As[32][68];
    __shared__ float Ws[32][68];
    const int tid = threadIdx.x;
    const int tx = tid & 15, ty = tid >> 4;
    const int m0 = blockIdx.y * 64;
    const int n0 = blockIdx.x * 64;
    const int lr = tid >> 3;
    const int lc = (tid & 7) << 2;
    float acc[4][4] = {};
    for (int k0 = 0; k0 < K; k0 += 32) {
        const float4 a0 = *(const float4*)(A + (size_t)(m0 + lr) * lda + k0 + lc);
        const float4 a1 = *(const float4*)(A + (size_t)(m0 + lr + 32) * lda + k0 + lc);
        const float4 b0 = *(const float4*)(W + (size_t)(n0 + lr) * K + k0 + lc);
        const float4 b1 = *(const float4*)(W + (size_t)(n0 + lr + 32) * K + k0 + lc);
        __syncthreads();
        As[lc+0][lr] = a0.x; As[lc+1][lr] = a0.y; As[lc+2][lr] = a0.z; As[lc+3][lr] = a0.w;
        As[lc+0][lr+32] = a1.x; As[lc+1][lr+32] = a1.y; As[lc+2][lr+32] = a1.z; As[lc+3][lr+32] = a1.w;
        Ws[lc+0][lr] = b0.x; Ws[lc+1][lr] = b0.y; Ws[lc+2][lr] = b0.z; Ws[lc+3][lr] = b0.w;
        Ws[lc+0][lr+32] = b1.x; Ws[lc+1][lr+32] = b1.y; Ws[lc+2][lr+32] = b1.z; Ws[lc+3][lr+32] = b1.w;
        __syncthreads();
        #pragma unroll
        for (int k = 0; k < 32; ++k) {
            const float4 a4 = *(const float4*)&As[k][ty << 2];
            const float4 b4 = *(const float4*)&Ws[k][tx << 2];
            const float a[4] = {a4.x, a4.y, a4.z, a4.w};
            const float b[4] = {b4.x, b4.y, b4.z, b4.w};
            #pragma unroll
            for (int i = 0; i < 4; ++i)
                #pragma unroll
                for (int j = 0; j < 4; ++j)
                    acc[i][j] = fmaf(a[i], b[j], acc[i][j]);
        }
    }
    const int mb = m0 + (ty << 2);
    const int nb = n0 + (tx << 2);
    #pragma unroll
    for (int i = 0; i < 4; ++i) {
        const size_t m = mb + i;
        #pragma unroll
        for (int j = 0; j < 4; ++j) {
            const int n = nb + j;
            C[m * ldc + n] = softplusf(acc[i][j] + bias[n]);
        }
    }
}

// ---------------------------------------------------------------------------
__global__ __launch_bounds__(256)
void cast_bf16_kernel(const float* __restrict__ src, __hip_bfloat16* __restrict__ dst, int n4)
{
    const int i = blockIdx.x * 256 + threadIdx.x;
    if (i >= n4) return;
    const float4 v = ((const float4*)src)[i];
    union { __hip_bfloat16 h[4]; short4 s; } o;
    o.h[0] = __float2bfloat16(v.x); o.h[1] = __float2bfloat16(v.y);
    o.h[2] = __float2bfloat16(v.z); o.h[3] = __float2bfloat16(v.w);
    ((short4*)dst)[i] = o.s;
}

__global__ __launch_bounds__(256)
void cast_pad_kernel(const float* __restrict__ src, __hip_bfloat16* __restrict__ dst,
                     int nrows, int K4, int total4)
{
    const int i = blockIdx.x * 256 + threadIdx.x;
    if (i >= total4) return;
    const int row = i / K4;
    float4 v = make_float4(0.f, 0.f, 0.f, 0.f);
    if (row < nrows) v = ((const float4*)src)[i];
    union { __hip_bfloat16 h[4]; short4 s; } o;
    o.h[0] = __float2bfloat16(v.x); o.h[1] = __float2bfloat16(v.y);
    o.h[2] = __float2bfloat16(v.z); o.h[3] = __float2bfloat16(v.w);
    ((short4*)dst)[i] = o.s;
}

__global__ __launch_bounds__(256)
void embed_kernel(const int* __restrict__ actions, const float* __restrict__ act_emb,
                  const float* __restrict__ pos_emb, __hip_bfloat16* __restrict__ xb)
{
    const int idx = blockIdx.x * 256 + threadIdx.x;   // MROWS*64
    const int e = idx & 63;
    const int m = idx >> 6;
    const int l = m & (HIST - 1);
    const int b = m >> 8;
    float v = pos_emb[l * DMODEL + e];
    if (l > 0) {
        const int a = actions[b * HIST + l - 1];
        v += act_emb[a * ADIM + e];
    }
    xb[(size_t)m * DMODEL + e] = __float2bfloat16(v);
}

// xcb[m,d] = bf16(silu(conv_b[d] + sum_k conv_w[d,k]*xi[l-3+k, d]))
// xi = xzb[:, 0:1024] with row stride 2048.
__global__ __launch_bounds__(256)
void conv_silu_kernel(const __hip_bfloat16* __restrict__ xzb, const float* __restrict__ cw,
                      const float* __restrict__ cb, __hip_bfloat16* __restrict__ xcb)
{
    const int idx = blockIdx.x * 256 + threadIdx.x;   // MROWS*DINNER
    const int d = idx & (DINNER - 1);
    const int m = idx >> 10;
    const int l = m & (HIST - 1);
    const float4 w = ((const float4*)cw)[d];
    const __hip_bfloat16* basep = xzb + (size_t)m * (2 * DINNER) + d;
    float acc = cb[d] + w.w * __bfloat162float(basep[0]);
    if (l >= 1) acc = fmaf(w.z, __bfloat162float(basep[-2 * DINNER]), acc);
    if (l >= 2) acc = fmaf(w.y, __bfloat162float(basep[-4 * DINNER]), acc);
    if (l >= 3) acc = fmaf(w.x, __bfloat162float(basep[-6 * DINNER]), acc);
    xcb[idx] = __float2bfloat16(siluf(acc));
}

// ---------------------------------------------------------------------------
// Selective scan. Wave = 4 channel-groups x 16 state-lanes.
// Per 16-step block: lane n preloads (dt, xc, z) for time l0+n; stores
// (dt, dt*xc) float2 to a bank-padded LDS slot. Per step: ONE ds_read_b64
// broadcast + DPP butterfly reduction (VALU pipe) — no ds_swizzle/bpermute.
__device__ __forceinline__ float dpp_add(float x, const int ctrl) {
    // fused v_add_f32_dpp: x + dpp_perm(x)
    switch (ctrl) {
    case 0xB1:  return x + __int_as_float(__builtin_amdgcn_update_dpp(0, __float_as_int(x), 0xB1, 0xF, 0xF, true));
    case 0x4E:  return x + __int_as_float(__builtin_amdgcn_update_dpp(0, __float_as_int(x), 0x4E, 0xF, 0xF, true));
    case 0x141: return x + __int_as_float(__builtin_amdgcn_update_dpp(0, __float_as_int(x), 0x141, 0xF, 0xF, true));
    default:    return x + __int_as_float(__builtin_amdgcn_update_dpp(0, __float_as_int(x), 0x140, 0xF, 0xF, true));
    }
}

__global__ __launch_bounds__(256)
void scan_kernel(const float* __restrict__ dtf, const float* __restrict__ bc,
                 const __hip_bfloat16* __restrict__ xcb, const __hip_bfloat16* __restrict__ zb,
                 const float* __restrict__ A_log, const float* __restrict__ D_p,
                 __hip_bfloat16* __restrict__ yb)
{
    __shared__ float2 bls[4][4][17];   // [wave][chan-group][j]; stride 17 breaks bank overlap
    const int tid = threadIdx.x;
    const int n   = tid & 15;
    const int wv  = tid >> 6;
    const int cg  = (tid >> 4) & 3;
    const int c = blockIdx.x * 16 + (tid >> 4);  // global channel (b,d)
    const int b = c >> 10;
    const int d = c & (DINNER - 1);
    const float A = -__expf(A_log[d * DSTATE + n]);
    const float Dp = D_p[d];
    float h = 0.f;
    const size_t row0 = (size_t)b * HIST;
    for (int l0 = 0; l0 < HIST; l0 += 16) {
        const size_t rj = row0 + l0 + n;          // this lane's assigned time row
        const float dtv = dtf[rj * DINNER + d];
        const float xcv = __bfloat162float(xcb[rj * DINNER + d]);
        const float zv  = __bfloat162float(zb [rj * 2 * DINNER + d]);
        bls[wv][cg][n] = make_float2(dtv, dtv * xcv);
        const float* bcp = bc + (row0 + l0) * 32 + 2 * n;
        float yreg = 0.f;
#define STEP(J) { \
        const float2 bq  = bls[wv][cg][J]; \
        const float2 bcv = *(const float2*)(bcp + (J) * 32); \
        const float dA = __expf(bq.x * A); \
        h = fmaf(dA, h, bq.y * bcv.x); \
        float ctr = h * bcv.y; \
        ctr = dpp_add(ctr, 0xB1); \
        ctr = dpp_add(ctr, 0x4E); \
        ctr = dpp_add(ctr, 0x141); \
        ctr = dpp_add(ctr, 0x140); \
        if (n == (J)) yreg = ctr; }
        STEP(0)  STEP(1)  STEP(2)  STEP(3)
        STEP(4)  STEP(5)  STEP(6)  STEP(7)
        STEP(8)  STEP(9)  STEP(10) STEP(11)
        STEP(12) STEP(13) STEP(14) STEP(15)
#undef STEP
        yb[rj * DINNER + d] = __float2bfloat16((yreg + xcv * Dp) * siluf(zv));
    }
}

// out[m,n] = b2[n] + sum_k h[m,k]*W2[n,k]
__global__ __launch_bounds__(256)
void ffn2_kernel(const float* __restrict__ h, const float* __restrict__ W2,
                 const float* __restrict__ b2, float* __restrict__ out)
{
    const int idx = blockIdx.x * 256 + threadIdx.x;   // MROWS*32
    const int n = idx & 31;
    const int m = idx >> 5;
    if (n >= 18) return;
    const float* hr = h + (size_t)m * DMODEL;
    const float* wr = W2 + (size_t)n * DMODEL;
    float acc = b2[n];
    for (int k = 0; k < DMODEL; k += 4) {
        const float4 hv = *(const float4*)(hr + k);
        const float4 wv = *(const float4*)(wr + k);
        acc = fmaf(hv.x, wv.x, acc);
        acc = fmaf(hv.y, wv.y, acc);
        acc = fmaf(hv.z, wv.z, acc);
        acc = fmaf(hv.w, wv.w, acc);
    }
    out[(size_t)m * 18 + n] = acc;
}

extern "C" void kernel_launch(void* const* d_in, const int* in_sizes, int n_in,
                              void* d_out, int out_size, void* d_ws, size_t ws_size,
                              hipStream_t stream)
{
    const float* obss    = (const float*)d_in[0];
    const int*   actions = (const int*)  d_in[1];
    const float* obs_W   = (const float*)d_in[2];
    const float* obs_b   = (const float*)d_in[3];
    const float* act_emb = (const float*)d_in[4];
    const float* pos_emb = (const float*)d_in[5];
    const float* W_in    = (const float*)d_in[6];
    const float* conv_w  = (const float*)d_in[7];
    const float* conv_b  = (const float*)d_in[8];
    const float* W_x     = (const float*)d_in[9];
    const float* W_dt    = (const float*)d_in[10];
    const float* b_dt    = (const float*)d_in[11];
    const float* A_log   = (const float*)d_in[12];
    const float* D_p     = (const float*)d_in[13];
    const float* W_out   = (const float*)d_in[14];
    const float* ffn_W1  = (const float*)d_in[15];
    const float* ffn_b1  = (const float*)d_in[16];
    const float* ffn_W2  = (const float*)d_in[17];
    const float* ffn_b2  = (const float*)d_in[18];
    float* out = (float*)d_out;

    // Workspace (MiB offsets, lifetime-aliased):
    //  0-8    xb   (bf16 M x 512)        8-40   xzb (bf16 M x 2048: xi|z)
    //  40-56  xcb  (bf16 M x 1024)       56-88  dtf (f32 M x 1024)
    //  88-104 yb   (bf16 M x 1024)       104-105 xdt (f32 M x 32)
    //  105-106 bcbuf (f32 M x 32)        106-110 wbuf (bf16 weight scratch)
    //  110-110.25 wxb (bf16 128 x 1024)
    //  prologue: obssb @8-72 (over xzb/xcb/dtf);  epilogue: hbuf @8-24
    const size_t MiB = 1024 * 1024;
    char* base = (char*)d_ws;
    __hip_bfloat16* xb    = (__hip_bfloat16*)(base);
    __hip_bfloat16* xzb   = (__hip_bfloat16*)(base + 8 * MiB);
    __hip_bfloat16* xcb   = (__hip_bfloat16*)(base + 40 * MiB);
    float*          dtf   = (float*)(base + 56 * MiB);
    __hip_bfloat16* yb    = (__hip_bfloat16*)(base + 88 * MiB);
    float*          xdt   = (float*)(base + 104 * MiB);
    float*          bcbuf = (float*)(base + 105 * MiB);
    __hip_bfloat16* wbuf  = (__hip_bfloat16*)(base + 106 * MiB);
    __hip_bfloat16* wxb   = (__hip_bfloat16*)(base + 110 * MiB);
    __hip_bfloat16* obssb = (__hip_bfloat16*)(base + 8 * MiB);
    float*          hbuf  = (float*)(base + 8 * MiB);

    // --- prologue ---
    cast_bf16_kernel<<<(MROWS * OBSDIM / 4) / 256, 256, 0, stream>>>(obss, obssb, MROWS * OBSDIM / 4);
    cast_pad_kernel<<<(512 * OBSDIM / 4) / 256, 256, 0, stream>>>(obs_W, wbuf, OBSOUT, OBSDIM / 4, 512 * OBSDIM / 4);
    embed_kernel<<<MROWS * ADIM / 256, 256, 0, stream>>>(actions, act_emb, pos_emb, xb);
    gemm_mfma<MEPI_TOK><<<dim3(4, MROWS / 128), 256, 0, stream>>>(
        obssb, OBSDIM, wbuf, nullptr, 0, xb, DMODEL, nullptr, ADIM, OBSOUT, OBSDIM, obs_b, pos_emb);

    for (int i = 0; i < NLAYERS; ++i) {
        // W_in: xzb = bf16(xb @ W_in^T), ld 2048 (xi | z)
        cast_bf16_kernel<<<(2 * DINNER * DMODEL / 4) / 256, 256, 0, stream>>>(
            W_in + (size_t)i * 2 * DINNER * DMODEL, wbuf, 2 * DINNER * DMODEL / 4);
        gemm_mfma<MEPI_BF16><<<dim3(2 * DINNER / 128, MROWS / 128), 256, 0, stream>>>(
            xb, DMODEL, wbuf, nullptr, 0, xzb, 2 * DINNER, nullptr, 0, 2 * DINNER, DMODEL,
            nullptr, nullptr);
        conv_silu_kernel<<<MROWS * DINNER / 256, 256, 0, stream>>>(
            xzb, conv_w + (size_t)i * DINNER * 4, conv_b + (size_t)i * DINNER, xcb);
        // W_x (mfma, split): xdt = xcb @ W_x^T[:32], bcbuf = packed (B,C)
        cast_pad_kernel<<<(128 * DINNER / 4) / 256, 256, 0, stream>>>(
            W_x + (size_t)i * 64 * DINNER, wxb, 64, DINNER / 4, 128 * DINNER / 4);
        gemm_mfma<MEPI_SPLIT><<<dim3(1, MROWS / 128), 256, 0, stream>>>(
            xcb, DINNER, wxb, xdt, 0, nullptr, 0, bcbuf, 0, 64, DINNER, nullptr, nullptr);
        // W_dt (f32, K=32, softplus): dtf
        gemm_f32_sp<<<dim3(DINNER / 64, MROWS / 64), 256, 0, stream>>>(
            xdt, 32, W_dt + (size_t)i * DINNER * DTRANK, dtf, DINNER, DINNER, DTRANK,
            b_dt + (size_t)i * DINNER);
        scan_kernel<<<(32 * DINNER) / 16, 256, 0, stream>>>(
            dtf, bcbuf, xcb, xzb + DINNER, A_log + (size_t)i * DINNER * DSTATE,
            D_p + (size_t)i * DINNER, yb);
        // W_out: xb = bf16(yb @ W_out^T)
        cast_bf16_kernel<<<(DMODEL * DINNER / 4) / 256, 256, 0, stream>>>(
            W_out + (size_t)i * DMODEL * DINNER, wbuf, DMODEL * DINNER / 4);
        gemm_mfma<MEPI_BF16><<<dim3(DMODEL / 128, MROWS / 128), 256, 0, stream>>>(
            yb, DINNER, wbuf, nullptr, 0, xb, DMODEL, nullptr, 0, DMODEL, DINNER, nullptr, nullptr);
    }

    cast_bf16_kernel<<<(DMODEL * DMODEL / 4) / 256, 256, 0, stream>>>(ffn_W1, wbuf, DMODEL * DMODEL / 4);
    gemm_mfma<MEPI_RELUF><<<dim3(DMODEL / 128, MROWS / 128), 256, 0, stream>>>(
        xb, DMODEL, wbuf, hbuf, DMODEL, nullptr, 0, nullptr, 0, DMODEL, DMODEL, ffn_b1, nullptr);
    ffn2_kernel<<<MROWS * 32 / 256, 256, 0, stream>>>(hbuf, ffn_W2, ffn_b2, out);
}